// Round 1
// baseline (1653.922 us; speedup 1.0000x reference)
//
#include <hip/hip_runtime.h>
#include <hip/hip_bf16.h>
#include <stdint.h>
#include <stddef.h>

#define VOCAB 32000
#define HID 256
#define BATCH 16
#define SEQ 256
#define TSTEPS 255          // S-1
#define NGATES 1024         // 4*HID
#define NWG 4               // scan workgroups (each owns 64 hidden units)
#define MROWS (TSTEPS*BATCH) // 4080

typedef __attribute__((ext_vector_type(8))) __bf16 bf16x8;
typedef __attribute__((ext_vector_type(8))) short short8;
typedef __attribute__((ext_vector_type(4))) float floatx4;

__device__ __forceinline__ float sigmoidf_(float x) {
    return 1.0f / (1.0f + __expf(-x));
}
__device__ __forceinline__ float tanhf_(float x) {
    return 2.0f / (1.0f + __expf(-2.0f * x)) - 1.0f;
}

// load 8 consecutive f32 (32B-aligned) -> bf16x8 fragment
__device__ __forceinline__ bf16x8 cvt8(const float* __restrict__ p) {
    const floatx4* q = (const floatx4*)p;
    floatx4 x = q[0], y = q[1];
    bf16x8 r;
    r[0] = (__bf16)x[0]; r[1] = (__bf16)x[1]; r[2] = (__bf16)x[2]; r[3] = (__bf16)x[3];
    r[4] = (__bf16)y[0]; r[5] = (__bf16)y[1]; r[6] = (__bf16)y[2]; r[7] = (__bf16)y[3];
    return r;
}

// ---------------- K0: f32 -> bf16 convert (W_lin, W_ih) ----------------
__global__ __launch_bounds__(256) void k_cvt(const float* __restrict__ src,
                                             __bf16* __restrict__ dst) {
    size_t i = ((size_t)blockIdx.x * 256 + threadIdx.x) * 8;
    bf16x8 r = cvt8(src + i);
    *(bf16x8*)(dst + i) = r;
}

// ---------------- K1: xw[t][n][b] = emb_eff[tok[b][t]] @ W_ih.T + b_ih + b_hh
// one block per t; 4 waves; wave w covers n in [w*256, w*256+256)
// xw stored in MFMA C-layout-friendly order: [t][n][b] (b innermost)
__global__ __launch_bounds__(256) void k_xw(const int* __restrict__ old,
                                            const float* __restrict__ emb,
                                            const __bf16* __restrict__ wih,
                                            const float* __restrict__ b_ih,
                                            const float* __restrict__ b_hh,
                                            float* __restrict__ xw) {
    int t = blockIdx.x;
    int tid = threadIdx.x;
    int wave = tid >> 6, lane = tid & 63, quad = lane >> 4, l16 = lane & 15;

    // A fragments: x[b=l16][k], k = kt*32 + quad*8 + j
    int tok = old[l16 * SEQ + t];
    bf16x8 a[8];
#pragma unroll
    for (int kt = 0; kt < 8; kt++) {
        if (tok == 0) {
            bf16x8 z;
#pragma unroll
            for (int j = 0; j < 8; j++) z[j] = (__bf16)0.0f;
            a[kt] = z;
        } else {
            a[kt] = cvt8(emb + (size_t)tok * HID + kt * 32 + quad * 8);
        }
    }

    float* xwt = xw + (size_t)t * NGATES * BATCH;
    for (int nt = 0; nt < 16; nt++) {
        int n = wave * 256 + nt * 16 + l16;
        floatx4 acc = {0.0f, 0.0f, 0.0f, 0.0f};
#pragma unroll
        for (int kt = 0; kt < 8; kt++) {
            bf16x8 bf = *(const bf16x8*)(wih + (size_t)n * HID + kt * 32 + quad * 8);
            acc = __builtin_amdgcn_mfma_f32_16x16x32_bf16(a[kt], bf, acc, 0, 0, 0);
        }
        float bias = b_ih[n] + b_hh[n];
        acc[0] += bias; acc[1] += bias; acc[2] += bias; acc[3] += bias;
        // C layout: m(batch) = quad*4+r, n-col = l16 -> contiguous float4 over b
        *(floatx4*)(xwt + n * BATCH + quad * 4) = acc;
    }
}

// ---------------- K2: the LSTM scan ----------------
// 4 WGs x 256 threads. WG g owns hidden units [64g, 64g+64); wave w owns 16 of them.
// W_hh fragments (bf16) live in VGPRs for the whole scan (128 VGPR/wave).
// h exchanged through global hbuf (slot t+1 holds h after step t; slot 0 = zeros).
__global__ __launch_bounds__(256) void k_scan(const float* __restrict__ W_hh,
                                              const float* __restrict__ xw,
                                              __bf16* __restrict__ hbuf,
                                              int* __restrict__ flags) {
    int wg = blockIdx.x;
    int tid = threadIdx.x;
    int wave = tid >> 6, lane = tid & 63, quad = lane >> 4, l16 = lane & 15;
    int j0 = wg * 64 + wave * 16;
    int jj = j0 + l16;  // this lane's hidden-unit column

    // Preload B fragments: B[k][n] = W_hh[gate*256 + jj][k]
    bf16x8 wf[4][8];
#pragma unroll
    for (int g = 0; g < 4; g++) {
        const float* wrow = W_hh + (size_t)(g * HID + jj) * HID;
#pragma unroll
        for (int kt = 0; kt < 8; kt++)
            wf[g][kt] = cvt8(wrow + kt * 32 + quad * 8);
    }

    float cr0 = 0.0f, cr1 = 0.0f, cr2 = 0.0f, cr3 = 0.0f;  // c state, b = quad*4 + r

    for (int t = 0; t < TSTEPS; t++) {
        if (t > 0) {
            if (tid == 0) {
                while (__hip_atomic_load(flags + (t - 1), __ATOMIC_RELAXED,
                                         __HIP_MEMORY_SCOPE_AGENT) < NWG) {}
            }
            __syncthreads();
            __builtin_amdgcn_fence(__ATOMIC_ACQUIRE, "agent");
        }
        // A fragments: h_prev[b=l16][k]
        const __bf16* hs = hbuf + (size_t)t * (BATCH * HID) + l16 * HID;
        bf16x8 a[8];
#pragma unroll
        for (int kt = 0; kt < 8; kt++)
            a[kt] = *(const bf16x8*)(hs + kt * 32 + quad * 8);

        const float* xwt = xw + (size_t)t * NGATES * BATCH;
        floatx4 acc[4];
#pragma unroll
        for (int g = 0; g < 4; g++)
            acc[g] = *(const floatx4*)(xwt + (size_t)(g * HID + jj) * BATCH + quad * 4);

#pragma unroll
        for (int g = 0; g < 4; g++)
#pragma unroll
            for (int kt = 0; kt < 8; kt++)
                acc[g] = __builtin_amdgcn_mfma_f32_16x16x32_bf16(a[kt], wf[g][kt], acc[g], 0, 0, 0);

        // elementwise gates; acc[0]=i, acc[1]=f, acc[2]=g, acc[3]=o
        __bf16* hout = hbuf + (size_t)(t + 1) * (BATCH * HID);
        float c[4] = {cr0, cr1, cr2, cr3};
#pragma unroll
        for (int r = 0; r < 4; r++) {
            float iv = sigmoidf_(acc[0][r]);
            float fv = sigmoidf_(acc[1][r]);
            float gv = tanhf_(acc[2][r]);
            float ov = sigmoidf_(acc[3][r]);
            float cn = fv * c[r] + iv * gv;
            float h = ov * tanhf_(cn);
            c[r] = cn;
            hout[(quad * 4 + r) * HID + jj] = (__bf16)h;
        }
        cr0 = c[0]; cr1 = c[1]; cr2 = c[2]; cr3 = c[3];

        __syncthreads();  // drain all waves' h stores (vmcnt(0) before barrier)
        if (tid == 0) {
            __hip_atomic_fetch_add(flags + t, 1, __ATOMIC_RELEASE,
                                   __HIP_MEMORY_SCOPE_AGENT);
        }
    }
}

// ---------------- K3: logits = hs @ W_lin.T + b_lin ----------------
// M=4080 (rows = t*16+b, stored at hbuf row m+16), N=32000, K=256
// 128x128 tile, 256 threads (2x2 waves of 64x64), K staged in 4 chunks of 64
#define K3_MT 128
#define K3_NT 128
#define K3_KC 64
#define K3_LDR 72  // shorts per LDS row (+8 pad -> 2-way-max bank aliasing, free)

__global__ __launch_bounds__(256) void k_proj(const __bf16* __restrict__ hbuf,
                                              const __bf16* __restrict__ wl,
                                              const float* __restrict__ b_lin,
                                              float* __restrict__ out) {
    __shared__ short lA[K3_MT * K3_LDR];
    __shared__ short lB[K3_NT * K3_LDR];

    int tid = threadIdx.x;
    int wave = tid >> 6, lane = tid & 63, quad = lane >> 4, l16 = lane & 15;
    int wm = wave >> 1, wn = wave & 1;
    int m0 = blockIdx.y * K3_MT;
    int n0 = blockIdx.x * K3_NT;

    floatx4 acc[4][4];
#pragma unroll
    for (int i = 0; i < 4; i++)
#pragma unroll
        for (int j = 0; j < 4; j++)
            acc[i][j] = (floatx4){0.0f, 0.0f, 0.0f, 0.0f};

    const __bf16* Abase = hbuf + (size_t)BATCH * HID;  // row m -> slot rows m+16

    int srow = tid >> 1;         // 0..127
    int scol = (tid & 1) * 32;   // shorts within the 64-wide K chunk

    for (int kc = 0; kc < 4; kc++) {
        int kbase = kc * K3_KC;
        // stage A (guard m < 4080)
        {
            int m = m0 + srow;
            const __bf16* src = Abase + (size_t)m * HID + kbase + scol;
#pragma unroll
            for (int i = 0; i < 4; i++) {
                short8 v = (short8)0;
                if (m < MROWS) v = *(const short8*)(src + i * 8);
                *(short8*)&lA[srow * K3_LDR + scol + i * 8] = v;
            }
        }
        // stage B
        {
            const __bf16* src = wl + (size_t)(n0 + srow) * HID + kbase + scol;
#pragma unroll
            for (int i = 0; i < 4; i++)
                *(short8*)&lB[srow * K3_LDR + scol + i * 8] = *(const short8*)(src + i * 8);
        }
        __syncthreads();
#pragma unroll
        for (int kt = 0; kt < 2; kt++) {
            int ko = kt * 32 + quad * 8;
            bf16x8 af[4], bf[4];
#pragma unroll
            for (int mt = 0; mt < 4; mt++)
                af[mt] = *(bf16x8*)&lA[(wm * 64 + mt * 16 + l16) * K3_LDR + ko];
#pragma unroll
            for (int nt = 0; nt < 4; nt++)
                bf[nt] = *(bf16x8*)&lB[(wn * 64 + nt * 16 + l16) * K3_LDR + ko];
#pragma unroll
            for (int mt = 0; mt < 4; mt++)
#pragma unroll
                for (int nt = 0; nt < 4; nt++)
                    acc[mt][nt] = __builtin_amdgcn_mfma_f32_16x16x32_bf16(
                        af[mt], bf[nt], acc[mt][nt], 0, 0, 0);
        }
        __syncthreads();
    }

    // epilogue: out[b][t][v], m = t*16 + b
#pragma unroll
    for (int nt = 0; nt < 4; nt++) {
        int n = n0 + wn * 64 + nt * 16 + l16;
        float bias = b_lin[n];
#pragma unroll
        for (int mt = 0; mt < 4; mt++) {
            int mbase = m0 + wm * 64 + mt * 16 + quad * 4;
#pragma unroll
            for (int r = 0; r < 4; r++) {
                int m = mbase + r;
                if (m < MROWS) {
                    int b = m & 15, t = m >> 4;
                    out[(size_t)b * TSTEPS * VOCAB + (size_t)t * VOCAB + n] =
                        acc[mt][nt][r] + bias;
                }
            }
        }
    }
}

// ---------------- launch ----------------
extern "C" void kernel_launch(void* const* d_in, const int* in_sizes, int n_in,
                              void* d_out, int out_size, void* d_ws, size_t ws_size,
                              hipStream_t stream) {
    const int*   old   = (const int*)d_in[0];
    const float* emb   = (const float*)d_in[1];
    const float* W_ih  = (const float*)d_in[2];
    const float* W_hh  = (const float*)d_in[3];
    const float* b_ih  = (const float*)d_in[4];
    const float* b_hh  = (const float*)d_in[5];
    const float* W_lin = (const float*)d_in[6];
    const float* b_lin = (const float*)d_in[7];
    float* out = (float*)d_out;

    char* ws = (char*)d_ws;
    // ws layout (all 16B aligned)
    float*  xw    = (float*)ws;                                   // 255*1024*16*4 = 16,711,680
    __bf16* wl    = (__bf16*)(ws + 16711680);                     // 32000*256*2   = 16,384,000
    __bf16* wih   = (__bf16*)(ws + 16711680 + 16384000);          // 1024*256*2    =    524,288
    __bf16* hbuf  = (__bf16*)(ws + 16711680 + 16384000 + 524288); // 256*4096*2    =  2,097,152
    int*    flags = (int*)(ws + 16711680 + 16384000 + 524288 + 2097152);

    // zero h slot 0 and the sync flags (ws is re-poisoned before every launch)
    hipMemsetAsync(hbuf, 0, (size_t)BATCH * HID * sizeof(__bf16), stream);
    hipMemsetAsync(flags, 0, 256 * sizeof(int), stream);

    k_cvt<<<dim3(VOCAB * HID / 2048), dim3(256), 0, stream>>>(W_lin, wl);
    k_cvt<<<dim3(NGATES * HID / 2048), dim3(256), 0, stream>>>(W_ih, wih);
    k_xw<<<dim3(TSTEPS), dim3(256), 0, stream>>>(old, emb, wih, b_ih, b_hh, xw);
    k_scan<<<dim3(NWG), dim3(256), 0, stream>>>(W_hh, xw, hbuf, flags);
    k_proj<<<dim3(VOCAB / K3_NT, (MROWS + K3_MT - 1) / K3_MT), dim3(256), 0, stream>>>(
        hbuf, wl, b_lin, out);
}